// Round 1
// baseline (99.123 us; speedup 1.0000x reference)
//
#include <hip/hip_runtime.h>
#include <hip/hip_fp16.h>

// SoftNCutsLoss via rank-2 separable factorization of the bilateral weight.
// w = exp(-(Iw-I0)^2/100)*wz(dz) ; exp(Iw*I0/50) ~= 1 + Iw*I0/50 (rel err <= 2e-4)
//  => w ~= [g(I0)]*[g(Iw)]*wz + [g(I0)*I0/50]*[g(Iw)*Iw]*wz,  g(u)=exp(-u^2/100)
// Pipeline (fused, this round):
//   fused   : per (pair, y-tile, x-half) block, stream x:
//             slice F=(g*p, g*I*p) staged in LDS as half2 -> 9-tap BoxY (pk_f16)
//             -> 9-deep register FIFO BoxX -> 3-tap z-comb via lane shuffles
//             -> write half2 V.   (U intermediate eliminated: -46 MB HBM)
//   contract: elementwise rank-2 recombine + EPS-pad den correction + fused
//             einsums + block reduce + replicated atomics
//   final   : 4 - sum_k (num+eps)/(den+eps)

constexpr int Pdim = 64;
constexpr int P3   = Pdim * Pdim * Pdim;   // 262144
constexpr int NREP = 16;

#define EPSF 2.2204460492503131e-16f

constexpr float WZ1   = 0.8290291181804004f;     // exp(-3/16)
constexpr float K2F   = 0.014426950408889634f;   // log2(e)/100
constexpr float C1F   = 0.02f;                   // 1/50
constexpr float WFULL = 81.0f * (1.0f + 2.0f * WZ1);

// ---------------------------------------------------------------------------
// Fused pass: BoxY (LDS slice, half2 packed taps) -> BoxX (register FIFO,
// streaming x) -> z-comb (wave shuffles; z == lane axis) -> V half2.
// Block: 256 threads = 4 waves; wave w owns output row y0+w, lanes = z.
// LDS slice: S[z*13 + y_in], y_in 0..11 (stride 13 words: gcd(13,32)=1 ->
// worst 2-way bank aliasing, free). Loader: thread loads rows w+{0,4,8}.
// x split in two halves (like old passx): X0=0 (36 slices, emit from i>=4)
// and X0=28 (36 slices + 4 zero-push tail, emit from i>=8).
// ---------------------------------------------------------------------------
template<int X0, int FIRSTW, bool TAIL>
__device__ __forceinline__ void fused_body(const float* __restrict__ Ib,
                                           const float* __restrict__ Pb,
                                           __half2* __restrict__ Vo,
                                           __half2* __restrict__ S,
                                           int w, int z, int ybase, bool isden) {
  int  gy[3]; bool oky[3];
#pragma unroll
  for (int j = 0; j < 3; ++j) {
    gy[j]  = ybase + w + 4 * j;
    oky[j] = ((unsigned)gy[j] < 64u);
  }
  const int soff0 = z * 13 + w;              // this thread's write/tap base

  float f0[9], f1[9];
#pragma unroll
  for (int i = 0; i < 9; ++i) { f0[i] = 0.f; f1[i] = 0.f; }
  float s0 = 0.f, s1 = 0.f;

  // triple-buffered raw slice registers; all indices static after unroll
  float LI[3][3], LP[3][3];
#pragma unroll
  for (int sidx = 0; sidx < 2; ++sidx) {     // preload slices X0, X0+1
#pragma unroll
    for (int j = 0; j < 3; ++j) {
      if (oky[j]) {
        const int a = ((X0 + sidx) << 12) + (gy[j] << 6) + z;
        LI[sidx][j] = Ib[a];
        LP[sidx][j] = isden ? 1.f : Pb[a];
      } else { LI[sidx][j] = 0.f; LP[sidx][j] = 0.f; }
    }
  }

  for (int o = 0; o < 2; ++o) {              // 2 x 18 slices (18%9==0, 18%3==0)
#pragma unroll
    for (int ii = 0; ii < 18; ++ii) {
      const int i   = o * 18 + ii;           // dynamic in o: addresses only
      const int x   = X0 + i;
      const int cur = ii % 3;                // static
      const int nxt = (ii + 2) % 3;          // static
      __syncthreads();                       // previous taps done with S
#pragma unroll
      for (int j = 0; j < 3; ++j) {
        float I  = LI[cur][j], p = LP[cur][j];
        float g  = exp2f(-I * I * K2F);
        float F0 = g * p;
        S[soff0 + 4 * j] = __floats2half2_rn(F0, F0 * I);
      }
      if (i + 2 < 36) {                      // prefetch slice x+2 (uniform)
#pragma unroll
        for (int j = 0; j < 3; ++j) {
          if (oky[j]) {
            const int a = ((x + 2) << 12) + (gy[j] << 6) + z;
            LI[nxt][j] = Ib[a];
            LP[nxt][j] = isden ? 1.f : Pb[a];
          } else { LI[nxt][j] = 0.f; LP[nxt][j] = 0.f; }
        }
      }
      __syncthreads();                       // slice x visible
      __half2 a2 = S[soff0];                 // 9-tap BoxY, packed f16 adds
#pragma unroll
      for (int dy = 1; dy < 9; ++dy) a2 = __hadd2(a2, S[soff0 + dy]);
      float2 yb = __half22float2(a2);
      const int r = ii % 9;                  // static (18 % 9 == 0)
      s0 += yb.x - f0[r]; f0[r] = yb.x;
      s1 += yb.y - f1[r]; f1[r] = yb.y;
      if (i >= FIRSTW) {                     // emit x_out = x-4
        float up0 = __shfl_up(s0, 1, 64),   up1 = __shfl_up(s1, 1, 64);
        float dn0 = __shfl_down(s0, 1, 64), dn1 = __shfl_down(s1, 1, 64);
        if (z == 0)  { up0 = 0.f; up1 = 0.f; }
        if (z == 63) { dn0 = 0.f; dn1 = 0.f; }
        float v0 = __builtin_fmaf(WZ1, up0 + dn0, s0);
        float v1 = __builtin_fmaf(WZ1, up1 + dn1, s1);
        Vo[(x - 4) << 12] = __floats2half2_rn(v0, v1);
      }
    }
  }
  if (TAIL) {                                // x=64..67: pure zero-push emits
#pragma unroll
    for (int k = 0; k < 4; ++k) {
      const int x = X0 + 36 + k;             // FIFO slot k holds slice x-9
      s0 -= f0[k]; s1 -= f1[k];
      float up0 = __shfl_up(s0, 1, 64),   up1 = __shfl_up(s1, 1, 64);
      float dn0 = __shfl_down(s0, 1, 64), dn1 = __shfl_down(s1, 1, 64);
      if (z == 0)  { up0 = 0.f; up1 = 0.f; }
      if (z == 63) { dn0 = 0.f; dn1 = 0.f; }
      float v0 = __builtin_fmaf(WZ1, up0 + dn0, s0);
      float v1 = __builtin_fmaf(WZ1, up1 + dn1, s1);
      Vo[(x - 4) << 12] = __floats2half2_rn(v0, v1);
    }
  }
}

__global__ __launch_bounds__(256)
void ncuts_fused(const float* __restrict__ batch, const float* __restrict__ preds,
                 __half2* __restrict__ V, float* __restrict__ acc) {
  __shared__ __half2 S[832];                 // 64 z * 13 words, 3.3 KB
  const int t = threadIdx.x;
  if (blockIdx.x == 0 && blockIdx.y == 0 && blockIdx.z == 0) {
    acc[t] = 0.f; acc[t + 256] = 0.f;        // zero NREP*32 = 512 accumulators
  }
  const int w = t >> 6, z = t & 63;
  const int pair = blockIdx.y;               // b*5 + c, c=0..3 pred, c=4 den
  const int b = pair / 5, c = pair - 5 * b;
  const bool isden = (c == 4);
  const int y0 = blockIdx.x * 4;             // output y tile base
  const float* Ib = batch + b * P3;
  const float* Pb = isden ? Ib : preds + (b * 4 + c) * P3;
  __half2* Vo = V + pair * P3 + ((y0 + w) << 6) + z;
  if (blockIdx.z == 0) fused_body< 0, 4, false>(Ib, Pb, Vo, S, w, z, y0 - 4, isden);
  else                 fused_body<28, 8, true >(Ib, Pb, Vo, S, w, z, y0 - 4, isden);
}

// ---------------------------------------------------------------------------
// Contract: rank-2 recombine, den boundary fix, fused einsums, block reduce.
// ---------------------------------------------------------------------------
__global__ __launch_bounds__(256)
void ncuts_contract(const float* __restrict__ batch, const float* __restrict__ preds,
                    const __half2* __restrict__ V, float* __restrict__ acc) {
  __shared__ float red[4][32];
  const int t = threadIdx.x;
  float pn[16], pd[16];
#pragma unroll
  for (int i = 0; i < 16; ++i) { pn[i] = 0.f; pd[i] = 0.f; }

#pragma unroll 1
  for (int it = 0; it < 2; ++it) {
    const int v = blockIdx.x * 512 + it * 256 + t;
    const int z = v & 63, y = (v >> 6) & 63, x = v >> 12;

    float a0[4], a1[4], gsum = 0.f;
#pragma unroll
    for (int b = 0; b < 4; ++b) {
      float I = batch[b * P3 + v];
      float g = exp2f(-I * I * K2F);
      a0[b] = g; a1[b] = g * I * C1F; gsum += g;
    }

    float ns[4] = {0.f, 0.f, 0.f, 0.f};
    float ds = 0.f;
#pragma unroll
    for (int b = 0; b < 4; ++b) {
#pragma unroll
      for (int c = 0; c < 5; ++c) {
        float2 u = __half22float2(V[(b * 5 + c) * P3 + v]);
        float zc = __builtin_fmaf(a0[b], u.x, a1[b] * u.y);
        if (c < 4) ns[c] += zc;
        else       ds    += zc;
      }
    }
    // den boundary correction: out-of-bounds image cells have w ~= g(I0)*wz(dz)
    float cx = (float)(9 - max(0, 4 - x) - max(0, x - 59));
    float cy = (float)(9 - max(0, 4 - y) - max(0, y - 59));
    float cz = 1.f + WZ1 * (float)((int)(z > 0) + (int)(z < 63));
    ds = __builtin_fmaf(gsum, WFULL - cx * cy * cz, ds);

#pragma unroll
    for (int b = 0; b < 4; ++b) {
#pragma unroll
      for (int k = 0; k < 4; ++k) {
        float p = preds[(b * 4 + k) * P3 + v];
        pn[b * 4 + k] = __builtin_fmaf(p, ns[k], pn[b * 4 + k]);
        pd[b * 4 + k] = __builtin_fmaf(p, ds,    pd[b * 4 + k]);
      }
    }
  }

#pragma unroll
  for (int i = 0; i < 16; ++i) {
#pragma unroll
    for (int off = 32; off > 0; off >>= 1) {
      pn[i] += __shfl_down(pn[i], off, 64);
      pd[i] += __shfl_down(pd[i], off, 64);
    }
  }
  const int wave = t >> 6, lane = t & 63;
  if (lane == 0) {
#pragma unroll
    for (int i = 0; i < 16; ++i) { red[wave][i] = pn[i]; red[wave][16 + i] = pd[i]; }
  }
  __syncthreads();
  if (t < 32) {
    float s = red[0][t] + red[1][t] + red[2][t] + red[3][t];
    atomicAdd(&acc[(blockIdx.x & (NREP - 1)) * 32 + t], s);
  }
}

__global__ void ncuts_final(const float* __restrict__ acc, float* __restrict__ out) {
  __shared__ float loss[16];
  int t = threadIdx.x;
  if (t < 16) {
    float n = 0.f, d = 0.f;
    for (int r = 0; r < NREP; ++r) { n += acc[r * 32 + t]; d += acc[r * 32 + 16 + t]; }
    loss[t] = (n + EPSF) / (d + EPSF);
  }
  __syncthreads();
  if (t < 4) {
    float s = loss[t * 4] + loss[t * 4 + 1] + loss[t * 4 + 2] + loss[t * 4 + 3];
    out[t] = 4.0f - s;
  }
}

// ===========================================================================
// Fallback (round-1 direct kernel) if the workspace is too small.
// ===========================================================================
constexpr int Rxy = 4;
constexpr int TX = 8, TY = 8;
constexpr int ZLEN = 2;
constexpr int RGX = 16, RGY = 16, RGZ = 10;
constexpr int YP = 17, ZP = 11;

__global__ __launch_bounds__(256, 2)
void ncuts_main(const float* __restrict__ batch, const float* __restrict__ preds,
                float* __restrict__ acc) {
  __shared__ float  sB[RGX][YP][ZP];
  __shared__ float4 sP[RGX][YP][ZP];
  __shared__ float  red[4][32];

  const int t = threadIdx.x;
  const int tx = t & 7, ty = (t >> 3) & 7, tzt = t >> 6;
  const int bx0 = blockIdx.x * TX, by0 = blockIdx.y * TY, bz0 = blockIdx.z * 8;
  const int x = bx0 + tx, y = by0 + ty, z0 = bz0 + tzt * ZLEN;
  const int zc = tzt * ZLEN;

  float  den[ZLEN];
  float4 num[ZLEN];
#pragma unroll
  for (int j = 0; j < ZLEN; ++j) { den[j] = 0.f; num[j] = make_float4(0.f, 0.f, 0.f, 0.f); }

  const float C1 = -0.014426950408889634f;
  const float LWZ1 = -0.27050531991668065f;

  for (int b = 0; b < 4; ++b) {
    __syncthreads();
    for (int idx = t; idx < RGX * RGY * RGZ; idx += 256) {
      int rz = idx % RGZ, rq = idx / RGZ, ry = rq % RGY, rx = rq / RGY;
      int gx = bx0 + rx - Rxy, gy = by0 + ry - Rxy, gz = bz0 + rz - 1;
      bool in = ((unsigned)gx < 64u) & ((unsigned)gy < 64u) & ((unsigned)gz < 64u);
      float v = EPSF; float4 pv = make_float4(EPSF, EPSF, EPSF, EPSF);
      if (in) {
        int gi = (gx * Pdim + gy) * Pdim + gz;
        v = batch[b * P3 + gi];
        const float* pp = preds + b * 4 * P3 + gi;
        pv.x = pp[0]; pv.y = pp[P3]; pv.z = pp[2 * P3]; pv.w = pp[3 * P3];
      }
      sB[rx][ry][rz] = v; sP[rx][ry][rz] = pv;
    }
    __syncthreads();

    float I0[ZLEN];
#pragma unroll
    for (int j = 0; j < ZLEN; ++j) I0[j] = sB[tx + Rxy][ty + Rxy][zc + 1 + j];

#pragma unroll 1
    for (int dy = 0; dy < 9; ++dy) {
#pragma unroll 3
      for (int dx = 0; dx < 9; ++dx) {
        const float*  cb = &sB[tx + dx][ty + dy][zc];
        const float4* cp = &sP[tx + dx][ty + dy][zc];
        float colB[ZLEN + 2]; float4 colP[ZLEN + 2];
#pragma unroll
        for (int j = 0; j < ZLEN + 2; ++j) { colB[j] = cb[j]; colP[j] = cp[j]; }
#pragma unroll
        for (int j = 0; j < ZLEN; ++j) {
#pragma unroll
          for (int dz = 0; dz < 3; ++dz) {
            float d = colB[j + dz] - I0[j];
            float arg = __builtin_fmaf(d * d, C1, (dz == 1) ? 0.f : LWZ1);
            float w = exp2f(arg);
            den[j] += w;
            float4 p = colP[j + dz];
            num[j].x = __builtin_fmaf(w, p.x, num[j].x);
            num[j].y = __builtin_fmaf(w, p.y, num[j].y);
            num[j].z = __builtin_fmaf(w, p.z, num[j].z);
            num[j].w = __builtin_fmaf(w, p.w, num[j].w);
          }
        }
      }
    }
  }

  float pn[16], pd[16];
#pragma unroll
  for (int i = 0; i < 16; ++i) { pn[i] = 0.f; pd[i] = 0.f; }
#pragma unroll
  for (int b = 0; b < 4; ++b) {
#pragma unroll
    for (int j = 0; j < ZLEN; ++j) {
      const float* pp = preds + b * 4 * P3 + ((x * Pdim + y) * Pdim + z0 + j);
      float nsv[4] = {num[j].x, num[j].y, num[j].z, num[j].w};
#pragma unroll
      for (int k = 0; k < 4; ++k) {
        float pv = pp[k * P3];
        pn[b * 4 + k] = __builtin_fmaf(pv, nsv[k], pn[b * 4 + k]);
        pd[b * 4 + k] = __builtin_fmaf(pv, den[j], pd[b * 4 + k]);
      }
    }
  }
#pragma unroll
  for (int i = 0; i < 16; ++i) {
#pragma unroll
    for (int off = 32; off > 0; off >>= 1) {
      pn[i] += __shfl_down(pn[i], off, 64);
      pd[i] += __shfl_down(pd[i], off, 64);
    }
  }
  const int wave = t >> 6, lane = t & 63;
  if (lane == 0) {
#pragma unroll
    for (int i = 0; i < 16; ++i) { red[wave][i] = pn[i]; red[wave][16 + i] = pd[i]; }
  }
  __syncthreads();
  if (t < 32) {
    float s = red[0][t] + red[1][t] + red[2][t] + red[3][t];
    int bid = blockIdx.x + 8 * (blockIdx.y + 8 * (int)blockIdx.z);
    atomicAdd(&acc[(bid & (NREP - 1)) * 32 + t], s);
  }
}

__global__ void ncuts_zero(float* __restrict__ acc) {
  int t = threadIdx.x;
  if (t < NREP * 32) acc[t] = 0.f;
}

// ===========================================================================
extern "C" void kernel_launch(void* const* d_in, const int* in_sizes, int n_in,
                              void* d_out, int out_size, void* d_ws, size_t ws_size,
                              hipStream_t stream) {
  const float* batch = (const float*)d_in[0];
  const float* preds = (const float*)d_in[1];
  float* out = (float*)d_out;

  const size_t fbytes = (size_t)20 * P3 * sizeof(__half2);   // 20 MB (V only now)
  const size_t need   = fbytes + 8192;
  if (ws_size >= need) {
    __half2* V   = (__half2*)((char*)d_ws + 256);
    float*   acc = (float*)((char*)d_ws + 256 + fbytes);     // NREP*32 floats
    hipLaunchKernelGGL(ncuts_fused, dim3(16, 20, 2), dim3(256), 0, stream,
                       batch, preds, V, acc);
    hipLaunchKernelGGL(ncuts_contract, dim3(512), dim3(256), 0, stream,
                       batch, preds, V, acc);
    hipLaunchKernelGGL(ncuts_final, dim3(1), dim3(64), 0, stream, acc, out);
  } else {
    float* acc = (float*)d_ws;
    hipLaunchKernelGGL(ncuts_zero, dim3(1), dim3(512), 0, stream, acc);
    hipLaunchKernelGGL(ncuts_main, dim3(8, 8, 8), dim3(256), 0, stream,
                       batch, preds, acc);
    hipLaunchKernelGGL(ncuts_final, dim3(1), dim3(64), 0, stream, acc, out);
  }
}